// Round 9
// baseline (2328.740 us; speedup 1.0000x reference)
//
#include <hip/hip_runtime.h>

// fp32 everywhere (reference is jnp.float32); captions int32.
//
// Round 9 = round 8 resubmitted unchanged: the round-8 bench died with the
// same infra error as round 5 ("MI355X container failed twice") before any
// kernel verdict; the round-5 precedent (byte-identical resubmit passed as
// round 6) plus a fresh audit (no divergent barriers, LDS 116KB < 160KB,
// all indices bounded, statically-indexed prefetch regs, graph-capture
// safe) says resubmit without conflating changes.
//
// Theory: round-7 scan was ~31 µs/step vs ~10 µs L2-BW floor: 8 barriers
// serialized short memory bursts (one latency ramp each, 8 waves/CU can't
// hide), and the P slice (L2-overflow -> L3) was read serially after
// softmax. This round:
//  (1) merge att2-partials + gh-partials into ONE phase (both read only
//      sh_h) -> one long stream, one ramp, one fewer barrier;
//  (2) register-prefetch the P slice (10 float4/thread, statically indexed)
//      at the top of the merged phase, ds_write to sh_P[49][384] before the
//      barrier -> P's L3 latency hides under ~640 FMAs; gi reads LDS;
//  (3) gh-reduce (tid<384) and att2-reduce (tid>=384) share one phase.
// LDS 116 KB (<160 KB gfx950). Everything else identical to round 7.

static __device__ __forceinline__ float my_tanh(float x) {
    x = fminf(fmaxf(x, -15.f), 15.f);
    float e = __expf(2.f * x);
    return (e - 1.f) / (e + 1.f);
}
static __device__ __forceinline__ float my_sigmoid(float x) {
    return 1.f / (1.f + __expf(-x));
}

// ---------------------------------------------------------------------------
// Tiled fp32 transpose: out[c*R + r] = in[r*ld_in + c]   (out shape [C][R])
// ---------------------------------------------------------------------------
__global__ __launch_bounds__(256) void transpose_f32(
    const float* __restrict__ in, float* __restrict__ out,
    int R, int C, int ld_in)
{
    __shared__ float tile[32][33];
    int tc = blockIdx.x * 32;
    int tr = blockIdx.y * 32;
    int tx = threadIdx.x & 31, ty = threadIdx.x >> 5;  // 32 x 8
    #pragma unroll
    for (int i = 0; i < 4; i++) {
        int r = tr + ty + i * 8, c = tc + tx;
        tile[ty + i * 8][tx] = (r < R && c < C) ? in[(long)r * ld_in + c] : 0.f;
    }
    __syncthreads();
    #pragma unroll
    for (int i = 0; i < 4; i++) {
        int c = tc + ty + i * 8, r = tr + tx;
        if (c < C && r < R) out[(long)c * R + r] = tile[tx][ty + i * 8];
    }
}

// ---------------------------------------------------------------------------
// Register-blocked fp32 GEMM: 128x128 C-tile, K-tiles of 16, 256 threads,
// 8x8 outputs/thread. Used for enc, att1, Gemb, P, fc.
// Requires K%16==0, N%4==0, lda%4==0. Row/col edges masked.
// ---------------------------------------------------------------------------
__global__ __launch_bounds__(256) void gemm_tile_f32(
    const float* __restrict__ A, int lda,
    const float* __restrict__ B, int ldb,
    const float* __restrict__ bias,
    float* __restrict__ C, int ldc,
    int M, int N, int K)
{
    __shared__ float As[16 * 132];
    __shared__ float Bs[16 * 132];
    const int tid = threadIdx.x;
    const int tx = tid & 15, ty = tid >> 4;
    const int rbase = blockIdx.y * 128;
    const int cbase = blockIdx.x * 128;

    float acc8[8][8];
    #pragma unroll
    for (int i = 0; i < 8; ++i)
        #pragma unroll
        for (int j = 0; j < 8; ++j) acc8[i][j] = 0.f;

    for (int kt = 0; kt < K; kt += 16) {
        #pragma unroll
        for (int u = 0; u < 2; ++u) {
            const int f = tid + u * 256;
            const int m = f >> 2, kq = f & 3;
            int row = rbase + m; if (row > M - 1) row = M - 1;
            const float4 v = *(const float4*)(A + (size_t)row * lda + kt + kq * 4);
            As[(kq * 4 + 0) * 132 + m] = v.x;
            As[(kq * 4 + 1) * 132 + m] = v.y;
            As[(kq * 4 + 2) * 132 + m] = v.z;
            As[(kq * 4 + 3) * 132 + m] = v.w;
        }
        #pragma unroll
        for (int u = 0; u < 2; ++u) {
            const int f = tid + u * 256;
            const int krow = f >> 5, nq = f & 31;
            int col = cbase + nq * 4; if (col > N - 4) col = N - 4;
            *(float4*)(&Bs[krow * 132 + nq * 4]) =
                *(const float4*)(B + (size_t)(kt + krow) * ldb + col);
        }
        __syncthreads();
        #pragma unroll
        for (int kk = 0; kk < 16; ++kk) {
            const float4 a0 = *(const float4*)(&As[kk * 132 + ty * 4]);
            const float4 a1 = *(const float4*)(&As[kk * 132 + 64 + ty * 4]);
            const float4 b0 = *(const float4*)(&Bs[kk * 132 + tx * 4]);
            const float4 b1 = *(const float4*)(&Bs[kk * 132 + 64 + tx * 4]);
            const float av[8] = {a0.x,a0.y,a0.z,a0.w,a1.x,a1.y,a1.z,a1.w};
            const float bv[8] = {b0.x,b0.y,b0.z,b0.w,b1.x,b1.y,b1.z,b1.w};
            #pragma unroll
            for (int i = 0; i < 8; ++i)
                #pragma unroll
                for (int j = 0; j < 8; ++j)
                    acc8[i][j] = fmaf(av[i], bv[j], acc8[i][j]);
        }
        __syncthreads();
    }

    float4 b4[2];
    #pragma unroll
    for (int cj = 0; cj < 2; ++cj) {
        const int col = cbase + cj * 64 + tx * 4;
        if (col < N && bias) {
            b4[cj].x = bias[col]; b4[cj].y = bias[col + 1];
            b4[cj].z = bias[col + 2]; b4[cj].w = bias[col + 3];
        } else { b4[cj].x = b4[cj].y = b4[cj].z = b4[cj].w = 0.f; }
    }
    #pragma unroll
    for (int i = 0; i < 8; ++i) {
        const int row = rbase + (i >> 2) * 64 + ty * 4 + (i & 3);
        if (row >= M) continue;
        #pragma unroll
        for (int cj = 0; cj < 2; ++cj) {
            const int col = cbase + cj * 64 + tx * 4;
            if (col >= N) continue;
            float4 o;
            o.x = acc8[i][cj * 4 + 0] + b4[cj].x;
            o.y = acc8[i][cj * 4 + 1] + b4[cj].y;
            o.z = acc8[i][cj * 4 + 2] + b4[cj].z;
            o.w = acc8[i][cj * 4 + 3] + b4[cj].w;
            *(float4*)(C + (size_t)row * ldc + col) = o;
        }
    }
}

// ---------------------------------------------------------------------------
// Gather embedding rows: out[m,:] = emb[caps[m],:]  (m = b*50+t, 3200 rows)
// ---------------------------------------------------------------------------
__global__ __launch_bounds__(256) void gather_emb(
    const int* __restrict__ caps, const float* __restrict__ emb,
    float* __restrict__ out)
{
    const int m = blockIdx.x;
    const int cap = caps[m];
    const float* src = emb + (size_t)cap * 512;
    float* dst = out + (size_t)m * 512;
    dst[threadIdx.x] = src[threadIdx.x];
    dst[threadIdx.x + 256] = src[threadIdx.x + 256];
}

// ---------------------------------------------------------------------------
// One fused decoder step. Grid 256 WGs = (sl 0..3) x (b 0..63), 512 threads.
// Phases: [h load | Gemb reg] -> [P prefetch issue; att2-partials +
// gh-partials merged; P ds_write] -> [gh-reduce || att2-reduce] -> scores ->
// softmax -> gi (from sh_P) -> GRU. h crosses steps at the kernel boundary.
// LDS 116 KB.
// ---------------------------------------------------------------------------
__global__ __launch_bounds__(512) void step_fused(
    const int t,
    const float* __restrict__ att1,   // [64*49][256]
    const float* __restrict__ W_da,   // [512][256] natural k-major
    const float* __restrict__ b_da,   // [256]
    const float* __restrict__ W_fa,   // [256]
    const float* __restrict__ b_fa,   // [1]
    const float* __restrict__ Wt_hh,  // [512][1536]
    const float* __restrict__ b_hh,   // [1536]
    const float* __restrict__ Gemb,   // [3200][1536] (includes b_ih)
    const float* __restrict__ P,      // [3136][1536] = enc @ W_ihc^T
    float* __restrict__ h_g,          // [64][512]
    float* __restrict__ Hbuf)         // [3200][512]
{
    __shared__ float sh_h[512];
    __shared__ float sh_P[49 * 384];    // staged P slice (75.3 KB)
    __shared__ float sh_a2p[8 * 256];   // att2 partials [kq][j]
    __shared__ float sh_att2[256];
    __shared__ float sh_red[392];
    __shared__ float sh_alpha[64];
    __shared__ float sh_gp[16 * 384];
    __shared__ float sh_gh[384];
    __shared__ float sh_gi[384];

    const int tid = threadIdx.x;
    const int b  = blockIdx.x & 63;
    const int sl = blockIdx.x >> 6;

    // ---- phase 0: stage h; register-prefetch Gemb
    sh_h[tid] = (t == 0) ? 0.f : h_g[(size_t)b * 512 + tid];
    float gemb_reg = 0.f;
    if (tid < 384) {
        const int n = (tid >> 7) * 512 + sl * 128 + (tid & 127);
        gemb_reg = Gemb[((size_t)b * 50 + t) * 1536 + n];
    }
    __syncthreads();

    // ---- phase 1 (merged): issue P prefetch, att2 partials, gh partials,
    //      then commit P to LDS. All loads overlap; one barrier.
    float4 pr[10];
    {
        const float* Pb = P + (size_t)b * 49 * 1536 + sl * 128;
        #pragma unroll
        for (int u = 0; u < 10; ++u) {
            const int i = tid + u * 512;          // i < 4704 = 49*96
            if (i < 4704) {
                const int l = i / 96, r = i - l * 96;
                const int g = r >> 5, jj = r & 31;
                pr[u] = *(const float4*)(Pb + (size_t)l * 1536 + g * 512 + jj * 4);
            }
        }
    }
    {   // att2 partials: jq = tid&63 (4 cols float4), kq = tid>>6 (8 k-groups)
        const int jq = tid & 63, kq = tid >> 6;
        const float4* w4 = (const float4*)(W_da + (size_t)(kq * 64) * 256 + jq * 4);
        const float* hk = sh_h + kq * 64;
        float4 a = {0.f, 0.f, 0.f, 0.f};
        #pragma unroll 8
        for (int k = 0; k < 64; ++k) {
            const float hv = hk[k];
            const float4 w = w4[(size_t)k * 64];   // +256 floats per k
            a.x = fmaf(hv, w.x, a.x); a.y = fmaf(hv, w.y, a.y);
            a.z = fmaf(hv, w.z, a.z); a.w = fmaf(hv, w.w, a.w);
        }
        *(float4*)&sh_a2p[kq * 256 + jq * 4] = a;
    }
    {   // gh partials: jq = tid&31 (4 j's float4 x 3 gates), kq = tid>>5 (16)
        const int jq = tid & 31, kq = tid >> 5;
        const int jbase = sl * 128 + jq * 4;
        const float* wrow = Wt_hh + (size_t)(kq * 32) * 1536 + jbase;
        const float* hk = sh_h + kq * 32;
        float4 a0 = {0.f,0.f,0.f,0.f}, a1 = {0.f,0.f,0.f,0.f},
               a2 = {0.f,0.f,0.f,0.f};
        #pragma unroll 8
        for (int k = 0; k < 32; ++k) {
            const float hv = hk[k];
            const float4 w0 = *(const float4*)(wrow + (size_t)k * 1536);
            const float4 w1 = *(const float4*)(wrow + (size_t)k * 1536 + 512);
            const float4 w2 = *(const float4*)(wrow + (size_t)k * 1536 + 1024);
            a0.x = fmaf(hv, w0.x, a0.x); a0.y = fmaf(hv, w0.y, a0.y);
            a0.z = fmaf(hv, w0.z, a0.z); a0.w = fmaf(hv, w0.w, a0.w);
            a1.x = fmaf(hv, w1.x, a1.x); a1.y = fmaf(hv, w1.y, a1.y);
            a1.z = fmaf(hv, w1.z, a1.z); a1.w = fmaf(hv, w1.w, a1.w);
            a2.x = fmaf(hv, w2.x, a2.x); a2.y = fmaf(hv, w2.y, a2.y);
            a2.z = fmaf(hv, w2.z, a2.z); a2.w = fmaf(hv, w2.w, a2.w);
        }
        float* gp = sh_gp + kq * 384;
        *(float4*)(gp + jq * 4)       = a0;
        *(float4*)(gp + 128 + jq * 4) = a1;
        *(float4*)(gp + 256 + jq * 4) = a2;
    }
    {   // commit P prefetch to LDS (loads have had the whole phase to land)
        #pragma unroll
        for (int u = 0; u < 10; ++u) {
            const int i = tid + u * 512;
            if (i < 4704) {
                const int l = i / 96, r = i - l * 96;
                *(float4*)&sh_P[l * 384 + r * 4] = pr[u];
            }
        }
    }
    __syncthreads();

    // ---- phase 2: gh-reduce (tid<384) || att2-reduce (tid>=384, 2 cols)
    if (tid < 384) {
        const int g = tid >> 7, jj = tid & 127;
        const int n = g * 512 + sl * 128 + jj;
        float s = 0.f;
        #pragma unroll
        for (int kq = 0; kq < 16; ++kq) s += sh_gp[kq * 384 + tid];
        sh_gh[tid] = s + b_hh[n];
    } else {
        const int j0 = (tid - 384) * 2;
        #pragma unroll
        for (int u = 0; u < 2; ++u) {
            const int j = j0 + u;
            float s = b_da[j];
            #pragma unroll
            for (int kq = 0; kq < 8; ++kq) s += sh_a2p[kq * 256 + j];
            sh_att2[j] = s;
        }
    }
    __syncthreads();

    // ---- phase 3: scores: 49 l x 8 chunks of 32 att-dims
    if (tid < 392) {
        const int l = tid >> 3, ch = tid & 7;
        const float4* a4 =
            (const float4*)(att1 + ((size_t)b * 49 + l) * 256 + ch * 32);
        const float* at2 = sh_att2 + ch * 32;
        const float* wf = W_fa + ch * 32;
        float s = 0.f;
        #pragma unroll
        for (int i = 0; i < 8; ++i) {
            const float4 v = a4[i];
            s += my_tanh(v.x + at2[i * 4 + 0]) * wf[i * 4 + 0];
            s += my_tanh(v.y + at2[i * 4 + 1]) * wf[i * 4 + 1];
            s += my_tanh(v.z + at2[i * 4 + 2]) * wf[i * 4 + 2];
            s += my_tanh(v.w + at2[i * 4 + 3]) * wf[i * 4 + 3];
        }
        sh_red[tid] = s;
    }
    __syncthreads();

    // ---- phase 4: softmax over L=49 on wave 0
    if (tid < 64) {
        float v = -1e30f;
        if (tid < 49) {
            const float* r = sh_red + tid * 8;
            v = r[0] + r[1] + r[2] + r[3] + r[4] + r[5] + r[6] + r[7] + b_fa[0];
        }
        float m = v;
        #pragma unroll
        for (int o = 32; o; o >>= 1) m = fmaxf(m, __shfl_xor(m, o));
        const float e = (tid < 49) ? __expf(v - m) : 0.f;
        float su = e;
        #pragma unroll
        for (int o = 32; o; o >>= 1) su += __shfl_xor(su, o);
        sh_alpha[tid] = e / su;
    }
    __syncthreads();

    // ---- phase 5: gi = Gemb + alpha . P   (P from LDS; thread = gate-col)
    if (tid < 384) {
        float gi = gemb_reg;
        const float* pp = sh_P + tid;
        #pragma unroll 7
        for (int l = 0; l < 49; ++l)
            gi = fmaf(sh_alpha[l], pp[l * 384], gi);
        sh_gi[tid] = gi;
    }
    __syncthreads();

    // ---- phase 6: GRU update for this slice's 128 j's
    if (tid < 128) {
        const int j = sl * 128 + tid;
        const float r  = my_sigmoid(sh_gi[tid] + sh_gh[tid]);
        const float z  = my_sigmoid(sh_gi[128 + tid] + sh_gh[128 + tid]);
        const float nn = my_tanh(sh_gi[256 + tid] + r * sh_gh[256 + tid]);
        const float hnew = (1.f - z) * nn + z * sh_h[j];
        h_g[(size_t)b * 512 + j] = hnew;
        Hbuf[((size_t)b * 50 + t) * 512 + j] = hnew;
    }
}

// ---------------------------------------------------------------------------
extern "C" void kernel_launch(void* const* d_in, const int* in_sizes, int n_in,
                              void* d_out, int out_size, void* d_ws, size_t ws_size,
                              hipStream_t stream) {
    const float* spatial = (const float*)d_in[0];
    const int*   captions= (const int*)d_in[1];
    const float* W_feat  = (const float*)d_in[2];
    const float* b_feat  = (const float*)d_in[3];
    const float* W_ea    = (const float*)d_in[4];
    const float* b_ea    = (const float*)d_in[5];
    const float* W_da    = (const float*)d_in[6];
    const float* b_da    = (const float*)d_in[7];
    const float* W_fa    = (const float*)d_in[8];
    const float* b_fa    = (const float*)d_in[9];
    const float* emb     = (const float*)d_in[10];
    const float* W_ih    = (const float*)d_in[11];
    const float* W_hh    = (const float*)d_in[12];
    const float* b_ih    = (const float*)d_in[13];
    const float* b_hh    = (const float*)d_in[14];
    const float* W_fc    = (const float*)d_in[15];
    const float* b_fc    = (const float*)d_in[16];
    float* out = (float*)d_out;

    // Workspace 25.7 MB. Gemb (19.7 MB) and P (19.3 MB) live in d_out
    // (128 MB) as scratch: both dead before the fc GEMM overwrites out.
    // Embt aliases Hbuf (consumed by the Gemb GEMM before scan writes Hbuf).
    char* ws = (char*)d_ws;
    float* Wt_ih = (float*)ws; ws += (size_t)1024 * 1536 * 4;   //  6,291,456
    float* Wt_hh = (float*)ws; ws += (size_t)512 * 1536 * 4;    //  3,145,728
    float* enc   = (float*)ws; ws += (size_t)3136 * 512 * 4;    //  6,422,528
    float* att1  = (float*)ws; ws += (size_t)3136 * 256 * 4;    //  3,211,264
    float* Hbuf  = (float*)ws; ws += (size_t)3200 * 512 * 4;    //  6,553,600
    float* h_g   = (float*)ws; ws += (size_t)64 * 512 * 4;      //    131,072
    const size_t NEED = 6291456ull + 3145728 + 6422528 + 3211264
                      + 6553600 + 131072;
    if (ws_size < NEED) return;

    float* Gemb = out;                          // [3200][1536] 19.66 MB
    float* P    = out + (size_t)3200 * 1536;    // [3136][1536] 19.27 MB
    float* Embt = Hbuf;

    dim3 blk(256);
    // Wt_ih[1024][1536] = W_ih^T  (rows 0..511 = emb part, 512.. = ctx part)
    transpose_f32<<<dim3(32, 48), blk, 0, stream>>>(W_ih, Wt_ih, 1536, 1024, 1024);
    // Wt_hh[512][1536] = W_hh^T
    transpose_f32<<<dim3(16, 48), blk, 0, stream>>>(W_hh, Wt_hh, 1536, 512, 512);

    // Embt[m,:] = emb[captions[m],:]          [3200,512]
    gather_emb<<<dim3(3200), blk, 0, stream>>>(captions, emb, Embt);

    // enc = spatial @ W_feat + b_feat         [3136,512]
    gemm_tile_f32<<<dim3(4, 25), blk, 0, stream>>>(spatial, 2048, W_feat, 512,
                                                   b_feat, enc, 512,
                                                   3136, 512, 2048);
    // att1 = enc @ W_ea + b_ea                [3136,256]
    gemm_tile_f32<<<dim3(2, 25), blk, 0, stream>>>(enc, 512, W_ea, 256, b_ea,
                                                   att1, 256, 3136, 256, 512);
    // Gemb = Embt @ Wt_ih[0:512,:] + b_ih     [3200,1536]
    gemm_tile_f32<<<dim3(12, 25), blk, 0, stream>>>(Embt, 512, Wt_ih, 1536, b_ih,
                                                    Gemb, 1536, 3200, 1536, 512);
    // P = enc @ Wt_ih[512:1024,:]             [3136,1536]  (no bias)
    gemm_tile_f32<<<dim3(12, 25), blk, 0, stream>>>(
        enc, 512, Wt_ih + (size_t)512 * 1536, 1536, (const float*)nullptr,
        P, 1536, 3136, 1536, 512);

    // recurrent scan: one fused kernel per step, 256 WGs (64 b x 4 slices);
    // h crosses steps at the kernel boundary (zero intra-step cross-WG deps)
    for (int t = 0; t < 50; ++t)
        step_fused<<<dim3(256), dim3(512), 0, stream>>>(
            t, att1, W_da, b_da, W_fa, b_fa, Wt_hh, b_hh, Gemb, P, h_g, Hbuf);

    // logits = Hbuf @ W_fc + b_fc -> d_out    [3200,10000]
    gemm_tile_f32<<<dim3(79, 25), blk, 0, stream>>>(Hbuf, 512, W_fc, 10000, b_fc,
                                                    out, 10000, 3200, 10000, 512);
}

// Round 10
// 1999.542 us; speedup vs baseline: 1.1646x; 1.1646x over previous
//
#include <hip/hip_runtime.h>

// fp32 everywhere (reference is jnp.float32); captions int32.
//
// Round 10: rounds 8/9 (merged-phase + P prefetch) were NEUTRAL (+3.5%) ->
// ramp theory wrong; the scan is per-CU L2-fetch-BYTES bound (~1.4 MB/WG/
// step). This round shrinks bytes via a 2-kernel step (stream order = sync):
//  A) score_step: 64 b x 4 j-chunks. Scores decompose over j, so each WG
//     reads only a 128 KB W_da slice (att2 dedup 4x) -> score_part[b][jc].
//  B) gate_step: 16 quads x 16 slices, 4 batches share every Wt_hh load
//     (192 KB slice, was 768), softmax from partials per wave, dedicated
//     prefetch warps stage P (73.5 KB) into LDS under the gh stream.
// Per-step per-WG bytes 1.4 MB -> ~0.3 MB. fc/enc/Gemb/P GEMMs unchanged.

static __device__ __forceinline__ float my_tanh(float x) {
    x = fminf(fmaxf(x, -15.f), 15.f);
    float e = __expf(2.f * x);
    return (e - 1.f) / (e + 1.f);
}
static __device__ __forceinline__ float my_sigmoid(float x) {
    return 1.f / (1.f + __expf(-x));
}

// ---------------------------------------------------------------------------
// Tiled fp32 transpose: out[c*R + r] = in[r*ld_in + c]   (out shape [C][R])
// ---------------------------------------------------------------------------
__global__ __launch_bounds__(256) void transpose_f32(
    const float* __restrict__ in, float* __restrict__ out,
    int R, int C, int ld_in)
{
    __shared__ float tile[32][33];
    int tc = blockIdx.x * 32;
    int tr = blockIdx.y * 32;
    int tx = threadIdx.x & 31, ty = threadIdx.x >> 5;  // 32 x 8
    #pragma unroll
    for (int i = 0; i < 4; i++) {
        int r = tr + ty + i * 8, c = tc + tx;
        tile[ty + i * 8][tx] = (r < R && c < C) ? in[(long)r * ld_in + c] : 0.f;
    }
    __syncthreads();
    #pragma unroll
    for (int i = 0; i < 4; i++) {
        int c = tc + ty + i * 8, r = tr + tx;
        if (c < C && r < R) out[(long)c * R + r] = tile[tx][ty + i * 8];
    }
}

// ---------------------------------------------------------------------------
// Register-blocked fp32 GEMM: 128x128 C-tile, K-tiles of 16, 256 threads,
// 8x8 outputs/thread. Used for enc, att1, Gemb, P, fc.
// Requires K%16==0, N%4==0, lda%4==0. Row/col edges masked.
// ---------------------------------------------------------------------------
__global__ __launch_bounds__(256) void gemm_tile_f32(
    const float* __restrict__ A, int lda,
    const float* __restrict__ B, int ldb,
    const float* __restrict__ bias,
    float* __restrict__ C, int ldc,
    int M, int N, int K)
{
    __shared__ float As[16 * 132];
    __shared__ float Bs[16 * 132];
    const int tid = threadIdx.x;
    const int tx = tid & 15, ty = tid >> 4;
    const int rbase = blockIdx.y * 128;
    const int cbase = blockIdx.x * 128;

    float acc8[8][8];
    #pragma unroll
    for (int i = 0; i < 8; ++i)
        #pragma unroll
        for (int j = 0; j < 8; ++j) acc8[i][j] = 0.f;

    for (int kt = 0; kt < K; kt += 16) {
        #pragma unroll
        for (int u = 0; u < 2; ++u) {
            const int f = tid + u * 256;
            const int m = f >> 2, kq = f & 3;
            int row = rbase + m; if (row > M - 1) row = M - 1;
            const float4 v = *(const float4*)(A + (size_t)row * lda + kt + kq * 4);
            As[(kq * 4 + 0) * 132 + m] = v.x;
            As[(kq * 4 + 1) * 132 + m] = v.y;
            As[(kq * 4 + 2) * 132 + m] = v.z;
            As[(kq * 4 + 3) * 132 + m] = v.w;
        }
        #pragma unroll
        for (int u = 0; u < 2; ++u) {
            const int f = tid + u * 256;
            const int krow = f >> 5, nq = f & 31;
            int col = cbase + nq * 4; if (col > N - 4) col = N - 4;
            *(float4*)(&Bs[krow * 132 + nq * 4]) =
                *(const float4*)(B + (size_t)(kt + krow) * ldb + col);
        }
        __syncthreads();
        #pragma unroll
        for (int kk = 0; kk < 16; ++kk) {
            const float4 a0 = *(const float4*)(&As[kk * 132 + ty * 4]);
            const float4 a1 = *(const float4*)(&As[kk * 132 + 64 + ty * 4]);
            const float4 b0 = *(const float4*)(&Bs[kk * 132 + tx * 4]);
            const float4 b1 = *(const float4*)(&Bs[kk * 132 + 64 + tx * 4]);
            const float av[8] = {a0.x,a0.y,a0.z,a0.w,a1.x,a1.y,a1.z,a1.w};
            const float bv[8] = {b0.x,b0.y,b0.z,b0.w,b1.x,b1.y,b1.z,b1.w};
            #pragma unroll
            for (int i = 0; i < 8; ++i)
                #pragma unroll
                for (int j = 0; j < 8; ++j)
                    acc8[i][j] = fmaf(av[i], bv[j], acc8[i][j]);
        }
        __syncthreads();
    }

    float4 b4[2];
    #pragma unroll
    for (int cj = 0; cj < 2; ++cj) {
        const int col = cbase + cj * 64 + tx * 4;
        if (col < N && bias) {
            b4[cj].x = bias[col]; b4[cj].y = bias[col + 1];
            b4[cj].z = bias[col + 2]; b4[cj].w = bias[col + 3];
        } else { b4[cj].x = b4[cj].y = b4[cj].z = b4[cj].w = 0.f; }
    }
    #pragma unroll
    for (int i = 0; i < 8; ++i) {
        const int row = rbase + (i >> 2) * 64 + ty * 4 + (i & 3);
        if (row >= M) continue;
        #pragma unroll
        for (int cj = 0; cj < 2; ++cj) {
            const int col = cbase + cj * 64 + tx * 4;
            if (col >= N) continue;
            float4 o;
            o.x = acc8[i][cj * 4 + 0] + b4[cj].x;
            o.y = acc8[i][cj * 4 + 1] + b4[cj].y;
            o.z = acc8[i][cj * 4 + 2] + b4[cj].z;
            o.w = acc8[i][cj * 4 + 3] + b4[cj].w;
            *(float4*)(C + (size_t)row * ldc + col) = o;
        }
    }
}

// ---------------------------------------------------------------------------
// Gather embedding rows: out[m,:] = emb[caps[m],:]  (m = b*50+t, 3200 rows)
// ---------------------------------------------------------------------------
__global__ __launch_bounds__(256) void gather_emb(
    const int* __restrict__ caps, const float* __restrict__ emb,
    float* __restrict__ out)
{
    const int m = blockIdx.x;
    const int cap = caps[m];
    const float* src = emb + (size_t)cap * 512;
    float* dst = out + (size_t)m * 512;
    dst[threadIdx.x] = src[threadIdx.x];
    dst[threadIdx.x + 256] = src[threadIdx.x + 256];
}

// ---------------------------------------------------------------------------
// Step kernel A: partial attention scores. Grid 256 = (b 0..63) x (jc 0..3),
// 256 threads. Each WG: att2 for att-cols [jc*64, jc*64+64) (W_da slice
// 128 KB), then partial scores over its 64 j's -> score_part[b][jc][l].
// Scores decompose over j because tanh is elementwise and the j-sum is
// linear in W_fa. No cross-WG deps; b_fa added in kernel B.
// ---------------------------------------------------------------------------
__global__ __launch_bounds__(256) void score_step(
    const int t,
    const float* __restrict__ att1,     // [64*49][256]
    const float* __restrict__ W_da,     // [512][256] natural k-major
    const float* __restrict__ b_da,     // [256]
    const float* __restrict__ W_fa,     // [256]
    const float* __restrict__ h_g,      // [64][512]
    float* __restrict__ score_part)     // [64][4][64]
{
    __shared__ float sh_h[512];
    __shared__ float sh_a2p[16 * 64];   // att2 partials [kq][j]
    __shared__ float sh_att2[64];
    __shared__ float sh_sp[196];

    const int tid = threadIdx.x;
    const int b  = blockIdx.x >> 2;
    const int jc = blockIdx.x & 3;

    sh_h[tid]       = (t == 0) ? 0.f : h_g[(size_t)b * 512 + tid];
    sh_h[256 + tid] = (t == 0) ? 0.f : h_g[(size_t)b * 512 + 256 + tid];
    __syncthreads();

    // att2 chunk: jq = tid&15 (4 cols as float4), kq = tid>>4 (16 groups of 32)
    {
        const int jq = tid & 15, kq = tid >> 4;
        const float4* w4 =
            (const float4*)(W_da + (size_t)(kq * 32) * 256 + jc * 64 + jq * 4);
        const float* hk = sh_h + kq * 32;
        float4 a = {0.f, 0.f, 0.f, 0.f};
        #pragma unroll 8
        for (int k = 0; k < 32; ++k) {
            const float hv = hk[k];
            const float4 w = w4[(size_t)k * 64];   // +256 floats per k
            a.x = fmaf(hv, w.x, a.x); a.y = fmaf(hv, w.y, a.y);
            a.z = fmaf(hv, w.z, a.z); a.w = fmaf(hv, w.w, a.w);
        }
        *(float4*)&sh_a2p[kq * 64 + jq * 4] = a;
    }
    __syncthreads();
    if (tid < 64) {
        float s = b_da[jc * 64 + tid];
        #pragma unroll
        for (int kq = 0; kq < 16; ++kq) s += sh_a2p[kq * 64 + tid];
        sh_att2[tid] = s;
    }
    __syncthreads();
    // partial scores: tid<196 = (l 0..48) x (q 0..3), 16 j's each
    if (tid < 196) {
        const int l = tid >> 2, q = tid & 3;
        const float4* a4 =
            (const float4*)(att1 + ((size_t)b * 49 + l) * 256 + jc * 64 + q * 16);
        const float* at2 = sh_att2 + q * 16;
        const float* wf  = W_fa + jc * 64 + q * 16;
        float s = 0.f;
        #pragma unroll
        for (int i = 0; i < 4; ++i) {
            const float4 v = a4[i];
            s += my_tanh(v.x + at2[i * 4 + 0]) * wf[i * 4 + 0];
            s += my_tanh(v.y + at2[i * 4 + 1]) * wf[i * 4 + 1];
            s += my_tanh(v.z + at2[i * 4 + 2]) * wf[i * 4 + 2];
            s += my_tanh(v.w + at2[i * 4 + 3]) * wf[i * 4 + 3];
        }
        sh_sp[tid] = s;
    }
    __syncthreads();
    if (tid < 49) {
        const float* r = sh_sp + tid * 4;
        score_part[((size_t)b * 4 + jc) * 64 + tid] = r[0] + r[1] + r[2] + r[3];
    }
}

// ---------------------------------------------------------------------------
// Step kernel B: softmax + gates + GRU. Grid 256 = (quad 0..15) x (sl 0..15)
// with bid = quad*16 + sl (bid%8 = sl%8 -> each XCD holds 2 Wt_hh slices),
// 512 threads. Each WG: 4 batches x 32 hidden j's.
//  phase 0: stage h (4 batches), per-wave softmax from score_part, Gemb reg.
//  phase 1: tid<384 = (cc 0..95, kq 0..3): gh partials, Wt_hh k-major
//           coalesced, 4 batches per weight load (512 FMA/thread);
//           tid>=384: 2 dedicated warps stage the P slice (73.5 KB) to LDS.
//  phase 2: gh reduce + gi = Gemb + alpha.P (from LDS).
//  phase 3: GRU update, write h_g + Hbuf.
// LDS ~92 KB. h crosses steps at the kernel boundary.
// ---------------------------------------------------------------------------
__global__ __launch_bounds__(512) void gate_step(
    const int t,
    const float* __restrict__ score_part, // [64][4][64]
    const float* __restrict__ b_fa,       // [1]
    const float* __restrict__ Wt_hh,      // [512][1536]
    const float* __restrict__ b_hh,       // [1536]
    const float* __restrict__ Gemb,       // [3200][1536] (includes b_ih)
    const float* __restrict__ P,          // [3136][1536] = enc @ W_ihc^T
    float* __restrict__ h_g,              // [64][512]
    float* __restrict__ Hbuf)             // [3200][512]
{
    __shared__ float sh_h[4 * 512];
    __shared__ float sh_alpha[4 * 64];
    __shared__ float sh_P[4 * 49 * 96];   // 18816 floats = 73.5 KB
    __shared__ float sh_gp[4 * 4 * 96];   // [kq][bb][cc]
    __shared__ float sh_gh[4 * 96];       // [bb][cc]
    __shared__ float sh_gi[4 * 96];

    const int tid = threadIdx.x;
    const int quad = blockIdx.x >> 4;
    const int sl   = blockIdx.x & 15;
    const int b0 = quad * 4;

    // ---- phase 0: stage h; Gemb -> reg; per-wave softmax from partials
    for (int i = tid; i < 2048; i += 512)
        sh_h[i] = (t == 0) ? 0.f : h_g[(size_t)b0 * 512 + i];
    float gemb_reg = 0.f;
    if (tid < 384) {
        const int bb = tid / 96, cc = tid - bb * 96;
        const int n = (cc >> 5) * 512 + sl * 32 + (cc & 31);
        gemb_reg = Gemb[((size_t)(b0 + bb) * 50 + t) * 1536 + n];
    }
    if (tid < 256) {                       // wave w = batch b0+w
        const int bb = tid >> 6, l = tid & 63;
        const float* sp = score_part + (size_t)(b0 + bb) * 256;
        float v = -1e30f;
        if (l < 49) v = sp[l] + sp[64 + l] + sp[128 + l] + sp[192 + l] + b_fa[0];
        float m = v;
        #pragma unroll
        for (int o = 32; o; o >>= 1) m = fmaxf(m, __shfl_xor(m, o));
        const float e = (l < 49) ? __expf(v - m) : 0.f;
        float su = e;
        #pragma unroll
        for (int o = 32; o; o >>= 1) su += __shfl_xor(su, o);
        sh_alpha[tid] = e / su;
    }
    __syncthreads();

    // ---- phase 1: gh partials (tid<384) || P prefetch crew (tid>=384)
    if (tid < 384) {
        const int cc = tid % 96, kq = tid / 96;      // kq 0..3, 128 k each
        const int n = (cc >> 5) * 512 + sl * 32 + (cc & 31);
        const float* wcol = Wt_hh + (size_t)(kq * 128) * 1536 + n;
        const float* h0 = sh_h + kq * 128;
        float a0 = 0.f, a1 = 0.f, a2 = 0.f, a3 = 0.f;
        #pragma unroll 8
        for (int k = 0; k < 128; ++k) {
            const float w = wcol[(size_t)k * 1536];
            a0 = fmaf(h0[k],        w, a0);
            a1 = fmaf(h0[512 + k],  w, a1);
            a2 = fmaf(h0[1024 + k], w, a2);
            a3 = fmaf(h0[1536 + k], w, a3);
        }
        sh_gp[(kq * 4 + 0) * 96 + cc] = a0;
        sh_gp[(kq * 4 + 1) * 96 + cc] = a1;
        sh_gp[(kq * 4 + 2) * 96 + cc] = a2;
        sh_gp[(kq * 4 + 3) * 96 + cc] = a3;
    } else {
        // stage P slice: rows (bb*49+l), 24 float4 per row (3 gates x 8)
        const int pt = tid - 384;
        const float* Pb = P + (size_t)b0 * 49 * 1536 + sl * 32;
        for (int i = pt; i < 4704; i += 128) {
            const int row = i / 24, cg = i - row * 24;
            const int g = cg >> 3, j4 = cg & 7;
            *(float4*)&sh_P[row * 96 + cg * 4] =
                *(const float4*)(Pb + (size_t)row * 1536 + g * 512 + j4 * 4);
        }
    }
    __syncthreads();

    // ---- phase 2: gh reduce + gi = Gemb + alpha . P (LDS)
    if (tid < 384) {
        const int bb = tid / 96, cc = tid - bb * 96;
        const int n = (cc >> 5) * 512 + sl * 32 + (cc & 31);
        float s = sh_gp[(0 * 4 + bb) * 96 + cc] + sh_gp[(1 * 4 + bb) * 96 + cc]
                + sh_gp[(2 * 4 + bb) * 96 + cc] + sh_gp[(3 * 4 + bb) * 96 + cc];
        sh_gh[bb * 96 + cc] = s + b_hh[n];

        float gi = gemb_reg;
        const float* pp = sh_P + (size_t)bb * 49 * 96 + cc;
        const float* al = sh_alpha + bb * 64;
        #pragma unroll 7
        for (int l = 0; l < 49; ++l)
            gi = fmaf(al[l], pp[l * 96], gi);
        sh_gi[bb * 96 + cc] = gi;
    }
    __syncthreads();

    // ---- phase 3: GRU update: tid<128 = (bb 0..3) x (jj 0..31)
    if (tid < 128) {
        const int bb = tid >> 5, jj = tid & 31;
        const int j = sl * 32 + jj;
        const float* gh = sh_gh + bb * 96;
        const float* gi = sh_gi + bb * 96;
        const float r  = my_sigmoid(gi[jj] + gh[jj]);
        const float z  = my_sigmoid(gi[32 + jj] + gh[32 + jj]);
        const float nn = my_tanh(gi[64 + jj] + r * gh[64 + jj]);
        const float hnew = (1.f - z) * nn + z * sh_h[bb * 512 + j];
        h_g[(size_t)(b0 + bb) * 512 + j] = hnew;
        Hbuf[((size_t)(b0 + bb) * 50 + t) * 512 + j] = hnew;
    }
}

// ---------------------------------------------------------------------------
extern "C" void kernel_launch(void* const* d_in, const int* in_sizes, int n_in,
                              void* d_out, int out_size, void* d_ws, size_t ws_size,
                              hipStream_t stream) {
    const float* spatial = (const float*)d_in[0];
    const int*   captions= (const int*)d_in[1];
    const float* W_feat  = (const float*)d_in[2];
    const float* b_feat  = (const float*)d_in[3];
    const float* W_ea    = (const float*)d_in[4];
    const float* b_ea    = (const float*)d_in[5];
    const float* W_da    = (const float*)d_in[6];
    const float* b_da    = (const float*)d_in[7];
    const float* W_fa    = (const float*)d_in[8];
    const float* b_fa    = (const float*)d_in[9];
    const float* emb     = (const float*)d_in[10];
    const float* W_ih    = (const float*)d_in[11];
    const float* W_hh    = (const float*)d_in[12];
    const float* b_ih    = (const float*)d_in[13];
    const float* b_hh    = (const float*)d_in[14];
    const float* W_fc    = (const float*)d_in[15];
    const float* b_fc    = (const float*)d_in[16];
    float* out = (float*)d_out;

    // Workspace 25.8 MB. Gemb (19.7 MB) and P (19.3 MB) live in d_out
    // (128 MB) as scratch: both dead before the fc GEMM overwrites out.
    // Embt aliases Hbuf (consumed by the Gemb GEMM before scan writes Hbuf).
    char* ws = (char*)d_ws;
    float* Wt_ih = (float*)ws; ws += (size_t)1024 * 1536 * 4;   //  6,291,456
    float* Wt_hh = (float*)ws; ws += (size_t)512 * 1536 * 4;    //  3,145,728
    float* enc   = (float*)ws; ws += (size_t)3136 * 512 * 4;    //  6,422,528
    float* att1  = (float*)ws; ws += (size_t)3136 * 256 * 4;    //  3,211,264
    float* Hbuf  = (float*)ws; ws += (size_t)3200 * 512 * 4;    //  6,553,600
    float* h_g   = (float*)ws; ws += (size_t)64 * 512 * 4;      //    131,072
    float* score = (float*)ws; ws += (size_t)64 * 4 * 64 * 4;   //     65,536
    const size_t NEED = 6291456ull + 3145728 + 6422528 + 3211264
                      + 6553600 + 131072 + 65536;
    if (ws_size < NEED) return;

    float* Gemb = out;                          // [3200][1536] 19.66 MB
    float* P    = out + (size_t)3200 * 1536;    // [3136][1536] 19.27 MB
    float* Embt = Hbuf;

    dim3 blk(256);
    // Wt_ih[1024][1536] = W_ih^T  (rows 0..511 = emb part, 512.. = ctx part)
    transpose_f32<<<dim3(32, 48), blk, 0, stream>>>(W_ih, Wt_ih, 1536, 1024, 1024);
    // Wt_hh[512][1536] = W_hh^T
    transpose_f32<<<dim3(16, 48), blk, 0, stream>>>(W_hh, Wt_hh, 1536, 512, 512);

    // Embt[m,:] = emb[captions[m],:]          [3200,512]
    gather_emb<<<dim3(3200), blk, 0, stream>>>(captions, emb, Embt);

    // enc = spatial @ W_feat + b_feat         [3136,512]
    gemm_tile_f32<<<dim3(4, 25), blk, 0, stream>>>(spatial, 2048, W_feat, 512,
                                                   b_feat, enc, 512,
                                                   3136, 512, 2048);
    // att1 = enc @ W_ea + b_ea                [3136,256]
    gemm_tile_f32<<<dim3(2, 25), blk, 0, stream>>>(enc, 512, W_ea, 256, b_ea,
                                                   att1, 256, 3136, 256, 512);
    // Gemb = Embt @ Wt_ih[0:512,:] + b_ih     [3200,1536]
    gemm_tile_f32<<<dim3(12, 25), blk, 0, stream>>>(Embt, 512, Wt_ih, 1536, b_ih,
                                                    Gemb, 1536, 3200, 1536, 512);
    // P = enc @ Wt_ih[512:1024,:]             [3136,1536]  (no bias)
    gemm_tile_f32<<<dim3(12, 25), blk, 0, stream>>>(
        enc, 512, Wt_ih + (size_t)512 * 1536, 1536, (const float*)nullptr,
        P, 1536, 3136, 1536, 512);

    // recurrent scan: 2 thin kernels per step (stream order = the only sync)
    for (int t = 0; t < 50; ++t) {
        score_step<<<dim3(256), dim3(256), 0, stream>>>(
            t, att1, W_da, b_da, W_fa, h_g, score);
        gate_step<<<dim3(256), dim3(512), 0, stream>>>(
            t, score, b_fa, Wt_hh, b_hh, Gemb, P, h_g, Hbuf);
    }

    // logits = Hbuf @ W_fc + b_fc -> d_out    [3200,10000]
    gemm_tile_f32<<<dim3(79, 25), blk, 0, stream>>>(Hbuf, 512, W_fc, 10000, b_fc,
                                                    out, 10000, 3200, 10000, 512);
}